// Round 1
// baseline (310.408 us; speedup 1.0000x reference)
//
#include <hip/hip_runtime.h>
#include <hip/hip_bf16.h>
#include <stdint.h>

#define NH 16
#define DH 64
#define BATCH 2
#define SEQ 2048
#define DMODEL 1024

typedef __attribute__((ext_vector_type(8))) short short8;
typedef __attribute__((ext_vector_type(4))) float f32x4;

#define MFMA16(a, b, c) __builtin_amdgcn_mfma_f32_16x16x32_bf16(a, b, c, 0, 0, 0)

__device__ inline unsigned short f2bf(float f) {
    union { float f; unsigned u; } v; v.f = f;
    unsigned r = v.u + 0x7fff + ((v.u >> 16) & 1);
    return (unsigned short)(r >> 16);
}

__device__ inline void gload_lds16(const unsigned short* g, unsigned short* l) {
    __builtin_amdgcn_global_load_lds((const __attribute__((address_space(1))) void*)g,
                                     (__attribute__((address_space(3))) void*)l, 16, 0, 0);
}

// ---------- fp32 -> bf16 convert (8 elems/thread) ----------
__global__ void k_cvt(const float* __restrict__ in, unsigned short* __restrict__ out) {
    size_t i = ((size_t)blockIdx.x * 256 + threadIdx.x) * 8;
    f32x4 a = *(const f32x4*)(in + i);
    f32x4 b = *(const f32x4*)(in + i + 4);
    short8 o;
    o[0] = (short)f2bf(a[0]); o[1] = (short)f2bf(a[1]);
    o[2] = (short)f2bf(a[2]); o[3] = (short)f2bf(a[3]);
    o[4] = (short)f2bf(b[0]); o[5] = (short)f2bf(b[1]);
    o[6] = (short)f2bf(b[2]); o[7] = (short)f2bf(b[3]);
    *(short8*)(out + i) = o;
}

// ---------- weight transpose [K][N] fp32 -> [N][K] bf16 ----------
__global__ void k_transpose_w(const float* __restrict__ w, unsigned short* __restrict__ out) {
    __shared__ float tile[32][33];
    int k0 = blockIdx.x * 32, n0 = blockIdx.y * 32;
    int tx = threadIdx.x, ty = threadIdx.y;  // 32 x 8
    #pragma unroll
    for (int j = 0; j < 32; j += 8)
        tile[ty + j][tx] = w[(size_t)(k0 + ty + j) * DMODEL + n0 + tx];
    __syncthreads();
    #pragma unroll
    for (int j = 0; j < 32; j += 8)
        out[(size_t)(n0 + ty + j) * DMODEL + k0 + tx] = f2bf(tile[tx][ty + j]);
}

// ---------- GEMM core: 128x128 tile, BK=32, 4 waves (2x2), m97 structure ----------
// A: [M][1024] bf16 row-major; Bt: [N][1024] bf16 (B transposed)
#define GEMM_BODY(A_, Bt_)                                                              \
    __shared__ __align__(16) unsigned short As[128 * 32];                               \
    __shared__ __align__(16) unsigned short Bs[128 * 32];                               \
    const int tid = threadIdx.x;                                                        \
    const int lane = tid & 63, wave = tid >> 6;                                         \
    const int wr = wave >> 1, wc = wave & 1;                                            \
    const int row0 = blockIdx.y * 128, col0 = blockIdx.x * 128;                         \
    const int frow = lane & 15, fk = (lane >> 4) * 8;                                   \
    f32x4 acc[4][4] = {};                                                               \
    const int lr = tid >> 2;                                                            \
    const int lc = (tid & 3) * 8;                                                       \
    const unsigned short* ga0 = A_ + (size_t)(row0 + lr) * 1024 + lc;                   \
    const unsigned short* gb0 = Bt_ + (size_t)(col0 + lr) * 1024 + lc;                  \
    for (int kt = 0; kt < 1024; kt += 32) {                                             \
        gload_lds16(ga0 + kt, As + wave * 512);                                         \
        gload_lds16(ga0 + 64 * 1024 + kt, As + 2048 + wave * 512);                      \
        gload_lds16(gb0 + kt, Bs + wave * 512);                                         \
        gload_lds16(gb0 + 64 * 1024 + kt, Bs + 2048 + wave * 512);                      \
        __syncthreads();                                                                \
        short8 af[4], bf[4];                                                            \
        _Pragma("unroll")                                                               \
        for (int m = 0; m < 4; ++m)                                                     \
            af[m] = *(const short8*)&As[(wr * 64 + m * 16 + frow) * 32 + fk];           \
        _Pragma("unroll")                                                               \
        for (int n = 0; n < 4; ++n)                                                     \
            bf[n] = *(const short8*)&Bs[(wc * 64 + n * 16 + frow) * 32 + fk];           \
        _Pragma("unroll")                                                               \
        for (int m = 0; m < 4; ++m)                                                     \
            _Pragma("unroll")                                                           \
            for (int n = 0; n < 4; ++n)                                                 \
                acc[m][n] = MFMA16(af[m], bf[n], acc[m][n]);                            \
        __syncthreads();                                                                \
    }

// QKV projection GEMM: N=3072 (q|k|v), scatters to [B,H,S,Dh] bf16, Q scaled by 1/8
__global__ __launch_bounds__(256) void k_gemm_qkv(
    const unsigned short* __restrict__ A, const unsigned short* __restrict__ Bt,
    const float* __restrict__ bq, const float* __restrict__ bk, const float* __restrict__ bv,
    unsigned short* __restrict__ qo, unsigned short* __restrict__ ko,
    unsigned short* __restrict__ vo)
{
    GEMM_BODY(A, Bt)
    const int p = col0 >> 10;  // 0=q 1=k 2=v, uniform per block
    const float* bias = (p == 0) ? bq : ((p == 1) ? bk : bv);
    unsigned short* dst = (p == 0) ? qo : ((p == 1) ? ko : vo);
    const float scl = (p == 0) ? 0.125f : 1.0f;
    #pragma unroll
    for (int m = 0; m < 4; ++m) {
        #pragma unroll
        for (int n = 0; n < 4; ++n) {
            int gcol = col0 + wc * 64 + n * 16 + frow;
            int hn = gcol & 1023;
            int h = hn >> 6, d = hn & 63;
            #pragma unroll
            for (int i = 0; i < 4; ++i) {
                int grow = row0 + wr * 64 + m * 16 + (lane >> 4) * 4 + i;
                int b = grow >> 11, s = grow & 2047;
                float v = (acc[m][n][i] + bias[hn]) * scl;
                dst[((size_t)(b * NH + h) * SEQ + s) * DH + d] = f2bf(v);
            }
        }
    }
}

// Output projection GEMM: fp32 out + bias
__global__ __launch_bounds__(256) void k_gemm_out(
    const unsigned short* __restrict__ A, const unsigned short* __restrict__ Bt,
    const float* __restrict__ bo, float* __restrict__ out)
{
    GEMM_BODY(A, Bt)
    #pragma unroll
    for (int m = 0; m < 4; ++m) {
        #pragma unroll
        for (int n = 0; n < 4; ++n) {
            int gcol = col0 + wc * 64 + n * 16 + frow;
            #pragma unroll
            for (int i = 0; i < 4; ++i) {
                int grow = row0 + wr * 64 + m * 16 + (lane >> 4) * 4 + i;
                out[(size_t)grow * DMODEL + gcol] = acc[m][n][i] + bo[gcol];
            }
        }
    }
}

// ---------- causal flash attention ----------
// Q,K,V: [B*H][S][DH] bf16 (Q pre-scaled by 1/8). O: [B][S][H*DH] bf16.
__global__ __launch_bounds__(256) void k_attn(
    const unsigned short* __restrict__ Q, const unsigned short* __restrict__ K,
    const unsigned short* __restrict__ V, unsigned short* __restrict__ O)
{
    __shared__ __align__(16) unsigned short Ks[64 * 80];
    __shared__ __align__(16) unsigned short Vt[64 * 80];
    __shared__ __align__(16) unsigned short Ps[4][16 * 80];
    const int tid = threadIdx.x, lane = tid & 63, wave = tid >> 6;
    const int bh = blockIdx.y, qt = blockIdx.x;
    const int q0 = qt * 64;
    const unsigned short* Qb = Q + (size_t)bh * SEQ * DH;
    const unsigned short* Kb = K + (size_t)bh * SEQ * DH;
    const unsigned short* Vb = V + (size_t)bh * SEQ * DH;
    const int frow = lane & 15, fk = (lane >> 4) * 8;

    short8 qf[2];
    #pragma unroll
    for (int t = 0; t < 2; ++t)
        qf[t] = *(const short8*)&Qb[(size_t)(q0 + wave * 16 + frow) * DH + t * 32 + fk];

    f32x4 oacc[4] = {};
    float mrow[4], lrow[4];
    #pragma unroll
    for (int i = 0; i < 4; ++i) { mrow[i] = -INFINITY; lrow[i] = 0.f; }

    const int sr = tid >> 3;        // 0..31 staging row
    const int sc8 = (tid & 7) * 8;  // staging col

    for (int kt = 0; kt <= qt; ++kt) {
        const int kv0 = kt * 64;
        __syncthreads();  // previous tile's LDS reads done
        #pragma unroll
        for (int hh = 0; hh < 2; ++hh) {
            int r = sr + hh * 32;
            short8 kk = *(const short8*)&Kb[(size_t)(kv0 + r) * DH + sc8];
            *(short8*)&Ks[r * 80 + sc8] = kk;
            short8 vv = *(const short8*)&Vb[(size_t)(kv0 + r) * DH + sc8];
            #pragma unroll
            for (int j = 0; j < 8; ++j) Vt[(sc8 + j) * 80 + r] = (unsigned short)vv[j];
        }
        __syncthreads();
        // QK^T
        f32x4 sc[4];
        #pragma unroll
        for (int n = 0; n < 4; ++n) {
            f32x4 s = {0.f, 0.f, 0.f, 0.f};
            #pragma unroll
            for (int t = 0; t < 2; ++t) {
                short8 kb = *(const short8*)&Ks[(n * 16 + frow) * 80 + t * 32 + fk];
                s = MFMA16(qf[t], kb, s);
            }
            sc[n] = s;
        }
        if (kt == qt) {  // causal mask on diagonal tile
            #pragma unroll
            for (int n = 0; n < 4; ++n) {
                int col = n * 16 + frow;
                #pragma unroll
                for (int i = 0; i < 4; ++i) {
                    int qrel = wave * 16 + (lane >> 4) * 4 + i;
                    if (col > qrel) sc[n][i] = -INFINITY;
                }
            }
        }
        // online softmax (rows = (lane>>4)*4+i of this wave's 16)
        #pragma unroll
        for (int i = 0; i < 4; ++i) {
            float mx = fmaxf(fmaxf(sc[0][i], sc[1][i]), fmaxf(sc[2][i], sc[3][i]));
            mx = fmaxf(mx, __shfl_xor(mx, 1));
            mx = fmaxf(mx, __shfl_xor(mx, 2));
            mx = fmaxf(mx, __shfl_xor(mx, 4));
            mx = fmaxf(mx, __shfl_xor(mx, 8));
            float mnew = fmaxf(mrow[i], mx);
            float scale = __expf(mrow[i] - mnew);
            float rsum = 0.f;
            #pragma unroll
            for (int n = 0; n < 4; ++n) {
                float pv = __expf(sc[n][i] - mnew);
                sc[n][i] = pv;
                rsum += pv;
            }
            rsum += __shfl_xor(rsum, 1);
            rsum += __shfl_xor(rsum, 2);
            rsum += __shfl_xor(rsum, 4);
            rsum += __shfl_xor(rsum, 8);
            lrow[i] = lrow[i] * scale + rsum;
            mrow[i] = mnew;
            #pragma unroll
            for (int n = 0; n < 4; ++n) oacc[n][i] *= scale;
        }
        // P -> wave-private LDS (bf16)
        #pragma unroll
        for (int n = 0; n < 4; ++n)
            #pragma unroll
            for (int i = 0; i < 4; ++i)
                Ps[wave][((lane >> 4) * 4 + i) * 80 + n * 16 + frow] = f2bf(sc[n][i]);
        asm volatile("s_waitcnt lgkmcnt(0)" ::: "memory");
        // PV
        short8 pa[2];
        #pragma unroll
        for (int t = 0; t < 2; ++t)
            pa[t] = *(const short8*)&Ps[wave][frow * 80 + t * 32 + fk];
        #pragma unroll
        for (int n = 0; n < 4; ++n) {
            #pragma unroll
            for (int t = 0; t < 2; ++t) {
                short8 vb = *(const short8*)&Vt[(n * 16 + frow) * 80 + t * 32 + fk];
                oacc[n] = MFMA16(pa[t], vb, oacc[n]);
            }
        }
    }
    // epilogue: O[b][s][h*64+d], normalized
    int b = bh >> 4, h = bh & 15;
    #pragma unroll
    for (int n = 0; n < 4; ++n) {
        #pragma unroll
        for (int i = 0; i < 4; ++i) {
            int qrow = q0 + wave * 16 + (lane >> 4) * 4 + i;
            float v = oacc[n][i] / lrow[i];
            O[((size_t)(b * SEQ + qrow)) * DMODEL + h * DH + n * 16 + frow] = f2bf(v);
        }
    }
}

extern "C" void kernel_launch(void* const* d_in, const int* in_sizes, int n_in,
                              void* d_out, int out_size, void* d_ws, size_t ws_size,
                              hipStream_t stream) {
    const float* x  = (const float*)d_in[0];
    const float* wq = (const float*)d_in[1];
    const float* bq = (const float*)d_in[2];
    const float* wk = (const float*)d_in[3];
    const float* bk = (const float*)d_in[4];
    const float* wv = (const float*)d_in[5];
    const float* bv = (const float*)d_in[6];
    const float* wo = (const float*)d_in[7];
    const float* bo = (const float*)d_in[8];
    float* out = (float*)d_out;

    char* w = (char*)d_ws;
    unsigned short* xb    = (unsigned short*)(w);
    unsigned short* wqkvT = (unsigned short*)(w + 8388608);
    unsigned short* woT   = (unsigned short*)(w + 14680064);
    unsigned short* qarr  = (unsigned short*)(w + 16777216);
    unsigned short* karr  = (unsigned short*)(w + 25165824);
    unsigned short* varr  = (unsigned short*)(w + 33554432);
    unsigned short* attnb = (unsigned short*)(w + 41943040);

    k_cvt<<<2048, 256, 0, stream>>>(x, xb);
    dim3 tb(32, 8);
    dim3 tg(32, 32);
    k_transpose_w<<<tg, tb, 0, stream>>>(wq, wqkvT);
    k_transpose_w<<<tg, tb, 0, stream>>>(wk, wqkvT + 1024 * 1024);
    k_transpose_w<<<tg, tb, 0, stream>>>(wv, wqkvT + 2 * 1024 * 1024);
    k_transpose_w<<<tg, tb, 0, stream>>>(wo, woT);
    k_gemm_qkv<<<dim3(24, 32), 256, 0, stream>>>(xb, wqkvT, bq, bk, bv, qarr, karr, varr);
    k_attn<<<dim3(32, 32), 256, 0, stream>>>(qarr, karr, varr, attnb);
    k_gemm_out<<<dim3(8, 32), 256, 0, stream>>>(attnb, woT, bo, out);
}